// Round 3
// baseline (218.041 us; speedup 1.0000x reference)
//
#include <hip/hip_runtime.h>
#include <hip/hip_bf16.h>

// ---------------------------------------------------------------------------
// SAGAN-style spatial self-attention, B=4 C=128 H=W=64 (N=4096), CQK=16.
// proj (5-wave blocks, MFMA) -> flash (1-wave blocks, JS=8 KV-split,
// K-prefetch, tree softmax) -> merge (bf16 partials).
// ---------------------------------------------------------------------------

#define BN 4
#define CC 128
#define NN 4096
#define DQK 16

typedef float f32x16 __attribute__((ext_vector_type(16)));
typedef short s16x8 __attribute__((ext_vector_type(8)));
typedef unsigned short u16;

union FragU { unsigned u[4]; s16x8 v; };

__device__ inline u16 to_bf16(float f) {
  __hip_bfloat16 h = __float2bfloat16(f);
  return *reinterpret_cast<u16*>(&h);          // avoid __builtin_bit_cast
}
__device__ inline unsigned pack_bf16(float lo, float hi) {
  return ((unsigned)to_bf16(hi) << 16) | (unsigned)to_bf16(lo);
}
__device__ inline float bf16lo_f(unsigned u) {
  return __builtin_bit_cast(float, u << 16);
}
__device__ inline float bf16hi_f(unsigned u) {
  return __builtin_bit_cast(float, u & 0xffff0000u);
}

// ---------------------------------------------------------------------------
// Kernel 1: fused QKV projection. grid = B*128 blocks x 320 threads (5 waves).
// Wave 0: Q(16)+K(16) stacked A-tile; waves 1..4: V row-tiles. Shared x-stage.
// Writes Qt[b][n][16] (bf16, *log2e), Kt[b][n][16], Vb[b][c][n].
// ---------------------------------------------------------------------------
__global__ __launch_bounds__(320) void proj_kernel(
    const float* __restrict__ x,
    const float* __restrict__ Wq, const float* __restrict__ bq,
    const float* __restrict__ Wk, const float* __restrict__ bk,
    const float* __restrict__ Wv, const float* __restrict__ bv,
    u16* __restrict__ Qt, u16* __restrict__ Kt, u16* __restrict__ Vb)
{
  __shared__ float xs[CC * 32];          // [c][nn], 16 KiB
  const int tid = threadIdx.x;
  const int wave = tid >> 6;
  const int lane = tid & 63;
  const int l31 = lane & 31, h = lane >> 5;
  const int bid = blockIdx.x;
  const int b = bid >> 7;
  const int n0 = (bid & 127) * 32;

  const float* xb = x + ((size_t)b * CC) * NN + n0;
  #pragma unroll
  for (int k = 0; k < 4; ++k) {
    int idx4 = tid + 320 * k;            // 0..1279, need <1024
    if (idx4 < 1024) {
      int c = idx4 >> 3;
      int nn4 = (idx4 & 7) * 4;
      float4 vv = *reinterpret_cast<const float4*>(xb + (size_t)c * NN + nn4);
      *reinterpret_cast<float4*>(&xs[c * 32 + nn4]) = vv;
    }
  }
  __syncthreads();

  // B-operand frags from x: lane holds col n=l31, k = 16*ks+8*h+e
  s16x8 bx[8];
  #pragma unroll
  for (int ks = 0; ks < 8; ++ks) {
    FragU f;
    #pragma unroll
    for (int q = 0; q < 4; ++q) {
      int c = 16 * ks + 8 * h + 2 * q;
      f.u[q] = pack_bf16(xs[c * 32 + l31], xs[(c + 1) * 32 + l31]);
    }
    bx[ks] = f.v;
  }

  f32x16 acc;
  #pragma unroll
  for (int r = 0; r < 16; ++r) acc[r] = 0.f;

  const float LOG2E = 1.44269504088896340736f;

  if (wave == 0) {
    // ---- Q+K stacked as one 32-row A tile ----
    const float* wrow = (l31 < 16) ? (Wq + (size_t)l31 * CC)
                                   : (Wk + (size_t)(l31 - 16) * CC);
    #pragma unroll
    for (int ks = 0; ks < 8; ++ks) {
      const float* wp = wrow + 16 * ks + 8 * h;
      float4 w0 = *reinterpret_cast<const float4*>(wp);
      float4 w1 = *reinterpret_cast<const float4*>(wp + 4);
      FragU a;
      a.u[0] = pack_bf16(w0.x, w0.y); a.u[1] = pack_bf16(w0.z, w0.w);
      a.u[2] = pack_bf16(w1.x, w1.y); a.u[3] = pack_bf16(w1.z, w1.w);
      acc = __builtin_amdgcn_mfma_f32_32x32x16_bf16(a.v, bx[ks], acc, 0, 0, 0);
    }
    #pragma unroll
    for (int r = 0; r < 16; ++r) {
      int row = (r & 3) + 8 * (r >> 2) + 4 * h;   // 0..31
      float val = acc[r];
      if (row < 16) {
        val = (val + bq[row]) * LOG2E;            // fold exp2 scaling into q
        Qt[((size_t)b * NN + n0 + l31) * DQK + row] = to_bf16(val);
      } else {
        val += bk[row - 16];
        Kt[((size_t)b * NN + n0 + l31) * DQK + (row - 16)] = to_bf16(val);
      }
    }
  } else {
    // ---- V row tile rt = wave-1 ----
    const int rt = wave - 1;
    const float* vrow = Wv + (size_t)(rt * 32 + l31) * CC;
    #pragma unroll
    for (int ks = 0; ks < 8; ++ks) {
      const float* wp = vrow + 16 * ks + 8 * h;
      float4 w0 = *reinterpret_cast<const float4*>(wp);
      float4 w1 = *reinterpret_cast<const float4*>(wp + 4);
      FragU a;
      a.u[0] = pack_bf16(w0.x, w0.y); a.u[1] = pack_bf16(w0.z, w0.w);
      a.u[2] = pack_bf16(w1.x, w1.y); a.u[3] = pack_bf16(w1.z, w1.w);
      acc = __builtin_amdgcn_mfma_f32_32x32x16_bf16(a.v, bx[ks], acc, 0, 0, 0);
    }
    #pragma unroll
    for (int r = 0; r < 16; ++r) {
      int e = rt * 32 + (r & 3) + 8 * (r >> 2) + 4 * h;
      Vb[((size_t)b * CC + e) * NN + n0 + l31] = to_bf16(acc[r] + bv[e]);
    }
  }
}

// ---------------------------------------------------------------------------
// Kernel 2: flash attention, 1 wave per (b, 32-row q-tile, kv-segment).
// Swapped QK^T (S^T = mfma(K,Q)): per-lane online softmax, O^T accumulate.
// K prefetched one tile ahead; V loads issued before S-MFMA (hidden under
// softmax). Partials (bf16 O, f32 m/l) per segment.
// ---------------------------------------------------------------------------
__global__ __launch_bounds__(64, 4) void flash_kernel(
    const u16* __restrict__ Qt, const u16* __restrict__ Kt,
    const u16* __restrict__ Vb,
    u16* __restrict__ Opart, float* __restrict__ mstat,
    float* __restrict__ lstat, int JS)
{
  const int lane = threadIdx.x;
  const int l31 = lane & 31, h = lane >> 5;
  const int bid = blockIdx.x;               // ((b*JS + sg)*128) + it
  const int it = bid & 127;
  const int bs = bid >> 7;
  const int b = bs / JS;
  const int sg = bs % JS;
  const int i0 = it * 32;
  const int seglen = NN / JS;
  const int j_begin = sg * seglen;
  const int ntiles = seglen / 32;

  f32x16 zero;
  #pragma unroll
  for (int r = 0; r < 16; ++r) zero[r] = 0.f;

  s16x8 qf = *reinterpret_cast<const s16x8*>(
      Qt + ((size_t)b * NN + i0 + l31) * DQK + 8 * h);

  const u16* Kb = Kt + (size_t)b * NN * DQK;
  const u16* Vbb = Vb + (size_t)b * CC * NN;

  f32x16 acc[4];
  #pragma unroll
  for (int ct = 0; ct < 4; ++ct) acc[ct] = zero;
  float m_run = -__builtin_inff();
  float l_run = 0.f;

  // preload K for tile 0
  s16x8 kf = *reinterpret_cast<const s16x8*>(
      Kb + (size_t)(j_begin + l31) * DQK + 8 * h);

  for (int t = 0; t < ntiles; ++t) {
    const int j0 = j_begin + t * 32;
    // V frags for THIS tile — issued now, consumed after softmax
    s16x8 vf[8];
    #pragma unroll
    for (int ct = 0; ct < 4; ++ct)
      #pragma unroll
      for (int ks = 0; ks < 2; ++ks)
        vf[ct * 2 + ks] = *reinterpret_cast<const s16x8*>(
            Vbb + (size_t)(ct * 32 + l31) * NN + j0 + 16 * ks + 8 * h);
    // prefetch next K
    s16x8 kf_next = kf;
    if (t + 1 < ntiles)
      kf_next = *reinterpret_cast<const s16x8*>(
          Kb + (size_t)(j0 + 32 + l31) * DQK + 8 * h);

    // S^T[j,i]: col i = l31 (lane-local q-row), rows j over regs
    f32x16 sv = __builtin_amdgcn_mfma_f32_32x32x16_bf16(kf, qf, zero, 0, 0, 0);
    kf = kf_next;

    // ---- online softmax (log2-domain), tree reductions ----
    float mx01 = fmaxf(sv[0], sv[1]),  mx23 = fmaxf(sv[2], sv[3]);
    float mx45 = fmaxf(sv[4], sv[5]),  mx67 = fmaxf(sv[6], sv[7]);
    float mx89 = fmaxf(sv[8], sv[9]),  mxab = fmaxf(sv[10], sv[11]);
    float mxcd = fmaxf(sv[12], sv[13]), mxef = fmaxf(sv[14], sv[15]);
    float tmax = fmaxf(fmaxf(fmaxf(mx01, mx23), fmaxf(mx45, mx67)),
                       fmaxf(fmaxf(mx89, mxab), fmaxf(mxcd, mxef)));
    float cmb = fmaxf(tmax, __shfl_xor(tmax, 32));
    float m_new = (cmb > m_run + 8.f) ? cmb : m_run;   // defer-max (T13)
    if (__any(m_new > m_run)) {
      float alpha = __builtin_amdgcn_exp2f(m_run - m_new);
      l_run *= alpha;
      #pragma unroll
      for (int ct = 0; ct < 4; ++ct)
        #pragma unroll
        for (int r = 0; r < 16; ++r) acc[ct][r] *= alpha;
      m_run = m_new;
    }

    float p[16];
    #pragma unroll
    for (int r = 0; r < 16; ++r)
      p[r] = __builtin_amdgcn_exp2f(sv[r] - m_run);
    float s01 = p[0] + p[1],  s23 = p[2] + p[3];
    float s45 = p[4] + p[5],  s67 = p[6] + p[7];
    float s89 = p[8] + p[9],  sab = p[10] + p[11];
    float scd = p[12] + p[13], sef = p[14] + p[15];
    l_run += ((s01 + s23) + (s45 + s67)) + ((s89 + sab) + (scd + sef));

    // pack P to bf16 pairs; exchange halves -> contiguous-j B-operand frags
    unsigned w[8], xw[8];
    #pragma unroll
    for (int q = 0; q < 8; ++q) w[q] = pack_bf16(p[2 * q], p[2 * q + 1]);
    #pragma unroll
    for (int q = 0; q < 8; ++q)
      xw[q] = (unsigned)__shfl_xor((int)w[q], 32);
    FragU f0, f1;
    f0.u[0] = h ? xw[2] : w[0];
    f0.u[1] = h ? xw[3] : w[1];
    f0.u[2] = h ? w[2] : xw[0];
    f0.u[3] = h ? w[3] : xw[1];
    f1.u[0] = h ? xw[6] : w[4];
    f1.u[1] = h ? xw[7] : w[5];
    f1.u[2] = h ? w[6] : xw[4];
    f1.u[3] = h ? w[7] : xw[5];

    // PV: O^T[c,i] += sum_j v[c,j] P[i,j]
    #pragma unroll
    for (int ct = 0; ct < 4; ++ct) {
      acc[ct] = __builtin_amdgcn_mfma_f32_32x32x16_bf16(vf[ct * 2 + 0], f0.v,
                                                        acc[ct], 0, 0, 0);
      acc[ct] = __builtin_amdgcn_mfma_f32_32x32x16_bf16(vf[ct * 2 + 1], f1.v,
                                                        acc[ct], 0, 0, 0);
    }
  }

  float l_tot = l_run + __shfl_xor(l_run, 32);

  u16* Ob = Opart + ((size_t)(b * JS + sg) * CC) * NN;
  #pragma unroll
  for (int ct = 0; ct < 4; ++ct)
    #pragma unroll
    for (int r = 0; r < 16; ++r) {
      int c = 32 * ct + (r & 3) + 8 * (r >> 2) + 4 * h;
      Ob[(size_t)c * NN + i0 + l31] = to_bf16(acc[ct][r]);
    }
  if (lane < 32) {
    mstat[((size_t)(b * JS + sg)) * NN + i0 + l31] = m_run;
    lstat[((size_t)(b * JS + sg)) * NN + i0 + l31] = l_tot;
  }
}

// ---------------------------------------------------------------------------
// Kernel 3: merge bf16 partials, normalize, out = gamma*O + x.
// grid = B*(N/128) blocks x 256 threads; each thread: 2 i-positions, 32 c.
// ---------------------------------------------------------------------------
template <int JS>
__global__ __launch_bounds__(256) void merge_kernel(
    const u16* __restrict__ Opart, const float* __restrict__ mstat,
    const float* __restrict__ lstat, const float* __restrict__ x,
    const float* __restrict__ gamma, float* __restrict__ out)
{
  const int t = threadIdx.x;
  const int p2 = t & 63, cg = t >> 6;
  const int bid = blockIdx.x;
  const int b = bid >> 5;
  const int i = ((bid & 31) << 7) + p2 * 2;     // pair of i positions

  float m0 = -__builtin_inff(), m1 = m0;
  float ms0[JS], ms1[JS];
  #pragma unroll
  for (int s = 0; s < JS; ++s) {
    const float* mp = mstat + ((size_t)(b * JS + s)) * NN + i;
    ms0[s] = mp[0]; ms1[s] = mp[1];
    m0 = fmaxf(m0, ms0[s]); m1 = fmaxf(m1, ms1[s]);
  }
  float d0 = 0.f, d1 = 0.f;
  float w0[JS], w1[JS];
  #pragma unroll
  for (int s = 0; s < JS; ++s) {
    const float* lp = lstat + ((size_t)(b * JS + s)) * NN + i;
    w0[s] = __builtin_amdgcn_exp2f(ms0[s] - m0);
    w1[s] = __builtin_amdgcn_exp2f(ms1[s] - m1);
    d0 += w0[s] * lp[0];
    d1 += w1[s] * lp[1];
  }
  const float g = gamma[0];
  const float g0 = g / d0, g1 = g / d1;
  #pragma unroll
  for (int s = 0; s < JS; ++s) { w0[s] *= g0; w1[s] *= g1; }

  #pragma unroll 8
  for (int cc = 0; cc < 32; ++cc) {
    int c = cg * 32 + cc;
    float o0 = 0.f, o1 = 0.f;
    #pragma unroll
    for (int s = 0; s < JS; ++s) {
      unsigned u = *reinterpret_cast<const unsigned*>(
          Opart + ((size_t)(b * JS + s) * CC + c) * NN + i);
      o0 += w0[s] * bf16lo_f(u);
      o1 += w1[s] * bf16hi_f(u);
    }
    size_t oidx = ((size_t)b * CC + c) * NN + i;
    float2 xv = *reinterpret_cast<const float2*>(x + oidx);
    float2 ov; ov.x = o0 + xv.x; ov.y = o1 + xv.y;
    *reinterpret_cast<float2*>(out + oidx) = ov;
  }
}

// ---------------------------------------------------------------------------
extern "C" void kernel_launch(void* const* d_in, const int* in_sizes, int n_in,
                              void* d_out, int out_size, void* d_ws,
                              size_t ws_size, hipStream_t stream)
{
  const float* x     = (const float*)d_in[0];
  const float* Wq    = (const float*)d_in[1];
  const float* bq    = (const float*)d_in[2];
  const float* Wk    = (const float*)d_in[3];
  const float* bk    = (const float*)d_in[4];
  const float* Wv    = (const float*)d_in[5];
  const float* bv    = (const float*)d_in[6];
  const float* gamma = (const float*)d_in[7];
  float* out = (float*)d_out;

  char* wsb = (char*)d_ws;
  const size_t szQ = (size_t)BN * NN * DQK * 2;        // 512 KiB
  const size_t szV = (size_t)BN * CC * NN * 2;         // 4 MiB
  const size_t base = 2 * szQ + szV;
  auto need = [&](size_t js) {
    return base + js * ((size_t)2 * BN * NN * 4 + (size_t)BN * CC * NN * 2);
  };
  int JS = 8;
  if (ws_size < need(8)) JS = 4;
  if (ws_size < need(4)) JS = 2;
  if (ws_size < need(2)) JS = 1;

  u16* Qt = (u16*)(wsb);
  u16* Kt = (u16*)(wsb + szQ);
  u16* Vb = (u16*)(wsb + 2 * szQ);
  float* mstat = (float*)(wsb + base);
  float* lstat = (float*)(wsb + base + (size_t)JS * BN * NN * 4);
  u16* Opart = (u16*)(wsb + base + (size_t)2 * JS * BN * NN * 4);

  proj_kernel<<<dim3(BN * 128), dim3(320), 0, stream>>>(
      x, Wq, bq, Wk, bk, Wv, bv, Qt, Kt, Vb);
  flash_kernel<<<dim3(BN * 128 * JS), dim3(64), 0, stream>>>(
      Qt, Kt, Vb, Opart, mstat, lstat, JS);
  if (JS == 8)
    merge_kernel<8><<<dim3(BN * 32), dim3(256), 0, stream>>>(
        Opart, mstat, lstat, x, gamma, out);
  else if (JS == 4)
    merge_kernel<4><<<dim3(BN * 32), dim3(256), 0, stream>>>(
        Opart, mstat, lstat, x, gamma, out);
  else if (JS == 2)
    merge_kernel<2><<<dim3(BN * 32), dim3(256), 0, stream>>>(
        Opart, mstat, lstat, x, gamma, out);
  else
    merge_kernel<1><<<dim3(BN * 32), dim3(256), 0, stream>>>(
        Opart, mstat, lstat, x, gamma, out);
}

// Round 5
// 130.114 us; speedup vs baseline: 1.6758x; 1.6758x over previous
//
#include <hip/hip_runtime.h>
#include <hip/hip_bf16.h>

// ---------------------------------------------------------------------------
// SAGAN-style spatial self-attention, B=4 C=128 H=W=64 (N=4096), CQK=16.
// proj (MFMA) -> flash (8-wave blocks, LDS-shared V tiles, swapped QK^T,
// per-lane online softmax, JS KV-split) -> merge (bf16 partials).
// ---------------------------------------------------------------------------

#define BN 4
#define CC 128
#define NN 4096
#define DQK 16
#define KVB 64

typedef float f32x16 __attribute__((ext_vector_type(16)));
typedef short s16x8 __attribute__((ext_vector_type(8)));
typedef unsigned short u16;

union FragU { unsigned u[4]; s16x8 v; };

__device__ inline u16 to_bf16(float f) {
  __hip_bfloat16 h = __float2bfloat16(f);
  return *reinterpret_cast<u16*>(&h);
}
__device__ inline unsigned pack_bf16(float lo, float hi) {
  return ((unsigned)to_bf16(hi) << 16) | (unsigned)to_bf16(lo);
}
__device__ inline float bf16lo_f(unsigned u) {
  return __builtin_bit_cast(float, u << 16);
}
__device__ inline float bf16hi_f(unsigned u) {
  return __builtin_bit_cast(float, u & 0xffff0000u);
}

// ---------------------------------------------------------------------------
// Kernel 1: fused QKV projection. grid = B*128 blocks x 320 threads (5 waves).
// Wave 0: Q(16)+K(16) stacked A-tile; waves 1..4: V row-tiles. Shared x-stage.
// Writes Qt[b][n][16] (bf16, *log2e), Kt[b][n][16], Vb[b][c][n].
// ---------------------------------------------------------------------------
__global__ __launch_bounds__(320) void proj_kernel(
    const float* __restrict__ x,
    const float* __restrict__ Wq, const float* __restrict__ bq,
    const float* __restrict__ Wk, const float* __restrict__ bk,
    const float* __restrict__ Wv, const float* __restrict__ bv,
    u16* __restrict__ Qt, u16* __restrict__ Kt, u16* __restrict__ Vb)
{
  __shared__ float xs[CC * 32];          // [c][nn], 16 KiB
  const int tid = threadIdx.x;
  const int wave = tid >> 6;
  const int lane = tid & 63;
  const int l31 = lane & 31, h = lane >> 5;
  const int bid = blockIdx.x;
  const int b = bid >> 7;
  const int n0 = (bid & 127) * 32;

  const float* xb = x + ((size_t)b * CC) * NN + n0;
  #pragma unroll
  for (int k = 0; k < 4; ++k) {
    int idx4 = tid + 320 * k;            // 0..1279, need <1024
    if (idx4 < 1024) {
      int c = idx4 >> 3;
      int nn4 = (idx4 & 7) * 4;
      float4 vv = *reinterpret_cast<const float4*>(xb + (size_t)c * NN + nn4);
      *reinterpret_cast<float4*>(&xs[c * 32 + nn4]) = vv;
    }
  }
  __syncthreads();

  // B-operand frags from x: lane holds col n=l31, k = 16*ks+8*h+e
  s16x8 bx[8];
  #pragma unroll
  for (int ks = 0; ks < 8; ++ks) {
    FragU f;
    #pragma unroll
    for (int q = 0; q < 4; ++q) {
      int c = 16 * ks + 8 * h + 2 * q;
      f.u[q] = pack_bf16(xs[c * 32 + l31], xs[(c + 1) * 32 + l31]);
    }
    bx[ks] = f.v;
  }

  f32x16 acc;
  #pragma unroll
  for (int r = 0; r < 16; ++r) acc[r] = 0.f;

  const float LOG2E = 1.44269504088896340736f;

  if (wave == 0) {
    const float* wrow = (l31 < 16) ? (Wq + (size_t)l31 * CC)
                                   : (Wk + (size_t)(l31 - 16) * CC);
    #pragma unroll
    for (int ks = 0; ks < 8; ++ks) {
      const float* wp = wrow + 16 * ks + 8 * h;
      float4 w0 = *reinterpret_cast<const float4*>(wp);
      float4 w1 = *reinterpret_cast<const float4*>(wp + 4);
      FragU a;
      a.u[0] = pack_bf16(w0.x, w0.y); a.u[1] = pack_bf16(w0.z, w0.w);
      a.u[2] = pack_bf16(w1.x, w1.y); a.u[3] = pack_bf16(w1.z, w1.w);
      acc = __builtin_amdgcn_mfma_f32_32x32x16_bf16(a.v, bx[ks], acc, 0, 0, 0);
    }
    #pragma unroll
    for (int r = 0; r < 16; ++r) {
      int row = (r & 3) + 8 * (r >> 2) + 4 * h;   // 0..31
      float val = acc[r];
      if (row < 16) {
        val = (val + bq[row]) * LOG2E;            // fold exp2 scaling into q
        Qt[((size_t)b * NN + n0 + l31) * DQK + row] = to_bf16(val);
      } else {
        val += bk[row - 16];
        Kt[((size_t)b * NN + n0 + l31) * DQK + (row - 16)] = to_bf16(val);
      }
    }
  } else {
    const int rt = wave - 1;
    const float* vrow = Wv + (size_t)(rt * 32 + l31) * CC;
    #pragma unroll
    for (int ks = 0; ks < 8; ++ks) {
      const float* wp = vrow + 16 * ks + 8 * h;
      float4 w0 = *reinterpret_cast<const float4*>(wp);
      float4 w1 = *reinterpret_cast<const float4*>(wp + 4);
      FragU a;
      a.u[0] = pack_bf16(w0.x, w0.y); a.u[1] = pack_bf16(w0.z, w0.w);
      a.u[2] = pack_bf16(w1.x, w1.y); a.u[3] = pack_bf16(w1.z, w1.w);
      acc = __builtin_amdgcn_mfma_f32_32x32x16_bf16(a.v, bx[ks], acc, 0, 0, 0);
    }
    #pragma unroll
    for (int r = 0; r < 16; ++r) {
      int e = rt * 32 + (r & 3) + 8 * (r >> 2) + 4 * h;
      Vb[((size_t)b * CC + e) * NN + n0 + l31] = to_bf16(acc[r] + bv[e]);
    }
  }
}

// ---------------------------------------------------------------------------
// Kernel 2: flash attention. 8-wave (512-thr) blocks; block owns 256 q-rows
// (32 per wave) and one KV segment. V tile [128c x 64j] staged to LDS
// (double-buffered, XOR-swizzled rows) shared by all 8 waves — coalesced
// global loads issued at phase top, ds_write after compute (T14), one
// barrier per KV iter. K frags from global (L1-hot). Swapped QK^T keeps
// softmax per-lane. Partials (bf16 O, f32 m/l) per segment.
// ---------------------------------------------------------------------------
__global__ __launch_bounds__(512, 4) void flash_kernel(
    const u16* __restrict__ Qt, const u16* __restrict__ Kt,
    const u16* __restrict__ Vb,
    u16* __restrict__ Opart, float* __restrict__ mstat,
    float* __restrict__ lstat, int JS)
{
  __shared__ u16 Vs[2][CC * KVB];        // 2 x 16 KiB, swizzled 128-B rows
  const int tid = threadIdx.x;
  const int wv = tid >> 6;
  const int lane = tid & 63;
  const int l31 = lane & 31, h = lane >> 5;
  const int qb = blockIdx.x & 15;        // q-block within (b,sg)
  const int bs = blockIdx.x >> 4;
  const int b = bs / JS, sg = bs % JS;
  const int i0 = qb * 256 + wv * 32;
  const int seglen = NN / JS;
  const int j_begin = sg * seglen;
  const int niter = seglen / KVB;

  // staging coords: thread stages 2 x 16B chunks (rows sc0 and 64+sc0)
  const int sc0 = tid >> 3;              // 0..63
  const int so = (tid & 7) * 16;         // byte offset in 128-B row
  const int sw0 = (sc0 & 7) << 4;        // row swizzle (same for sc0, sc0+64)

  const u16* Kb = Kt + (size_t)b * NN * DQK;
  const u16* Vbb = Vb + (size_t)b * CC * NN;

  s16x8 qf = *reinterpret_cast<const s16x8*>(
      Qt + ((size_t)b * NN + i0 + l31) * DQK + 8 * h);

  f32x16 zero;
  #pragma unroll
  for (int r = 0; r < 16; ++r) zero[r] = 0.f;
  f32x16 acc[4];
  #pragma unroll
  for (int ct = 0; ct < 4; ++ct) acc[ct] = zero;
  float m_run = -__builtin_inff();
  float l_run = 0.f;

  // prologue: stage tile 0, load K frags for iter 0
  {
    s16x8 g0 = *reinterpret_cast<const s16x8*>(
        Vbb + (size_t)sc0 * NN + j_begin + so / 2);
    s16x8 g1 = *reinterpret_cast<const s16x8*>(
        Vbb + (size_t)(64 + sc0) * NN + j_begin + so / 2);
    *reinterpret_cast<s16x8*>(&Vs[0][sc0 * KVB + ((so ^ sw0) >> 1)]) = g0;
    *reinterpret_cast<s16x8*>(&Vs[0][(64 + sc0) * KVB + ((so ^ sw0) >> 1)]) = g1;
  }
  s16x8 kf0 = *reinterpret_cast<const s16x8*>(
      Kb + (size_t)(j_begin + l31) * DQK + 8 * h);
  s16x8 kf1 = *reinterpret_cast<const s16x8*>(
      Kb + (size_t)(j_begin + 32 + l31) * DQK + 8 * h);
  __syncthreads();

  const int rsw = (l31 & 7) << 4;        // read-side row swizzle

  for (int t = 0; t < niter; ++t) {
    const int cur = t & 1;
    // issue next-tile loads first (overlap with compute below)
    s16x8 g0, g1, nk0, nk1;
    const bool more = (t + 1 < niter);
    if (more) {
      const int jn = j_begin + (t + 1) * KVB;
      g0 = *reinterpret_cast<const s16x8*>(
          Vbb + (size_t)sc0 * NN + jn + so / 2);
      g1 = *reinterpret_cast<const s16x8*>(
          Vbb + (size_t)(64 + sc0) * NN + jn + so / 2);
      nk0 = *reinterpret_cast<const s16x8*>(
          Kb + (size_t)(jn + l31) * DQK + 8 * h);
      nk1 = *reinterpret_cast<const s16x8*>(
          Kb + (size_t)(jn + 32 + l31) * DQK + 8 * h);
    }

    #pragma unroll
    for (int s = 0; s < 2; ++s) {
      // S^T[j,i] = mfma(K,Q): col i = l31, rows j over regs
      f32x16 sv = __builtin_amdgcn_mfma_f32_32x32x16_bf16(
          s ? kf1 : kf0, qf, zero, 0, 0, 0);

      // ---- per-lane online softmax (log2-domain), tree reductions ----
      float mx01 = fmaxf(sv[0], sv[1]),  mx23 = fmaxf(sv[2], sv[3]);
      float mx45 = fmaxf(sv[4], sv[5]),  mx67 = fmaxf(sv[6], sv[7]);
      float mx89 = fmaxf(sv[8], sv[9]),  mxab = fmaxf(sv[10], sv[11]);
      float mxcd = fmaxf(sv[12], sv[13]), mxef = fmaxf(sv[14], sv[15]);
      float tmax = fmaxf(fmaxf(fmaxf(mx01, mx23), fmaxf(mx45, mx67)),
                         fmaxf(fmaxf(mx89, mxab), fmaxf(mxcd, mxef)));
      float cmb = fmaxf(tmax, __shfl_xor(tmax, 32));
      float m_new = (cmb > m_run + 8.f) ? cmb : m_run;   // defer-max (T13)
      if (__any(m_new > m_run)) {
        float alpha = __builtin_amdgcn_exp2f(m_run - m_new);
        l_run *= alpha;
        #pragma unroll
        for (int ct = 0; ct < 4; ++ct)
          #pragma unroll
          for (int r = 0; r < 16; ++r) acc[ct][r] *= alpha;
        m_run = m_new;
      }

      float p[16];
      #pragma unroll
      for (int r = 0; r < 16; ++r)
        p[r] = __builtin_amdgcn_exp2f(sv[r] - m_run);
      float s01 = p[0] + p[1],  s23 = p[2] + p[3];
      float s45 = p[4] + p[5],  s67 = p[6] + p[7];
      float s89 = p[8] + p[9],  sab = p[10] + p[11];
      float scd = p[12] + p[13], sef = p[14] + p[15];
      l_run += ((s01 + s23) + (s45 + s67)) + ((s89 + sab) + (scd + sef));

      // pack P pairs, half-exchange -> contiguous-j B-operand frags
      unsigned w[8], xw[8];
      #pragma unroll
      for (int q = 0; q < 8; ++q) w[q] = pack_bf16(p[2 * q], p[2 * q + 1]);
      #pragma unroll
      for (int q = 0; q < 8; ++q)
        xw[q] = (unsigned)__shfl_xor((int)w[q], 32);
      FragU f0, f1;
      f0.u[0] = h ? xw[2] : w[0];
      f0.u[1] = h ? xw[3] : w[1];
      f0.u[2] = h ? w[2] : xw[0];
      f0.u[3] = h ? w[3] : xw[1];
      f1.u[0] = h ? xw[6] : w[4];
      f1.u[1] = h ? xw[7] : w[5];
      f1.u[2] = h ? w[6] : xw[4];
      f1.u[3] = h ? w[7] : xw[5];

      // PV: O^T[c,i] += sum_j V[c,j] P[i,j]; V frags from swizzled LDS
      #pragma unroll
      for (int ct = 0; ct < 4; ++ct) {
        const int c = 32 * ct + l31;
        s16x8 va = *reinterpret_cast<const s16x8*>(
            &Vs[cur][c * KVB + (((s * 64 + h * 16) ^ rsw) >> 1)]);
        s16x8 vb2 = *reinterpret_cast<const s16x8*>(
            &Vs[cur][c * KVB + (((s * 64 + 32 + h * 16) ^ rsw) >> 1)]);
        acc[ct] = __builtin_amdgcn_mfma_f32_32x32x16_bf16(va, f0.v,
                                                          acc[ct], 0, 0, 0);
        acc[ct] = __builtin_amdgcn_mfma_f32_32x32x16_bf16(vb2, f1.v,
                                                          acc[ct], 0, 0, 0);
      }
    }

    if (more) {
      *reinterpret_cast<s16x8*>(
          &Vs[cur ^ 1][sc0 * KVB + ((so ^ sw0) >> 1)]) = g0;
      *reinterpret_cast<s16x8*>(
          &Vs[cur ^ 1][(64 + sc0) * KVB + ((so ^ sw0) >> 1)]) = g1;
      kf0 = nk0; kf1 = nk1;
    }
    __syncthreads();
  }

  float l_tot = l_run + __shfl_xor(l_run, 32);

  u16* Ob = Opart + ((size_t)(b * JS + sg) * CC) * NN;
  #pragma unroll
  for (int ct = 0; ct < 4; ++ct)
    #pragma unroll
    for (int r = 0; r < 16; ++r) {
      int c = 32 * ct + (r & 3) + 8 * (r >> 2) + 4 * h;
      Ob[(size_t)c * NN + i0 + l31] = to_bf16(acc[ct][r]);
    }
  if (lane < 32) {
    mstat[((size_t)(b * JS + sg)) * NN + i0 + l31] = m_run;
    lstat[((size_t)(b * JS + sg)) * NN + i0 + l31] = l_tot;
  }
}

// ---------------------------------------------------------------------------
// Kernel 3: merge bf16 partials, normalize, out = gamma*O + x.
// grid = B*256 blocks x 256 threads; thread = 2 i-positions x 4 channels.
// ---------------------------------------------------------------------------
template <int JS>
__global__ __launch_bounds__(256) void merge_kernel(
    const u16* __restrict__ Opart, const float* __restrict__ mstat,
    const float* __restrict__ lstat, const float* __restrict__ x,
    const float* __restrict__ gamma, float* __restrict__ out)
{
  const int tid = threadIdx.x;
  const int il = tid & 63;                   // i-pair lane
  const int cg = tid >> 6;                   // 0..3
  const int bid = blockIdx.x;
  const int b = bid >> 8;
  const int rem = bid & 255;
  const int i = (((rem >> 3) << 6) + il) * 2;   // even i, pair (i, i+1)
  const int c0 = ((rem & 7) * 4 + cg) * 4;      // 4 channels

  float m0 = -__builtin_inff(), m1 = m0;
  float ms0[JS], ms1[JS];
  #pragma unroll
  for (int s = 0; s < JS; ++s) {
    const float* mp = mstat + ((size_t)(b * JS + s)) * NN + i;
    ms0[s] = mp[0]; ms1[s] = mp[1];
    m0 = fmaxf(m0, ms0[s]); m1 = fmaxf(m1, ms1[s]);
  }
  float d0 = 0.f, d1 = 0.f;
  float w0[JS], w1[JS];
  #pragma unroll
  for (int s = 0; s < JS; ++s) {
    const float* lp = lstat + ((size_t)(b * JS + s)) * NN + i;
    w0[s] = __builtin_amdgcn_exp2f(ms0[s] - m0);
    w1[s] = __builtin_amdgcn_exp2f(ms1[s] - m1);
    d0 += w0[s] * lp[0];
    d1 += w1[s] * lp[1];
  }
  const float g = gamma[0];
  const float g0 = g / d0, g1 = g / d1;
  #pragma unroll
  for (int s = 0; s < JS; ++s) { w0[s] *= g0; w1[s] *= g1; }

  #pragma unroll
  for (int cc = 0; cc < 4; ++cc) {
    int c = c0 + cc;
    float o0 = 0.f, o1 = 0.f;
    #pragma unroll
    for (int s = 0; s < JS; ++s) {
      unsigned u = *reinterpret_cast<const unsigned*>(
          Opart + ((size_t)(b * JS + s) * CC + c) * NN + i);
      o0 += w0[s] * bf16lo_f(u);
      o1 += w1[s] * bf16hi_f(u);
    }
    size_t oidx = ((size_t)b * CC + c) * NN + i;
    float2 xv = *reinterpret_cast<const float2*>(x + oidx);
    float2 ov; ov.x = o0 + xv.x; ov.y = o1 + xv.y;
    *reinterpret_cast<float2*>(out + oidx) = ov;
  }
}

// ---------------------------------------------------------------------------
extern "C" void kernel_launch(void* const* d_in, const int* in_sizes, int n_in,
                              void* d_out, int out_size, void* d_ws,
                              size_t ws_size, hipStream_t stream)
{
  const float* x     = (const float*)d_in[0];
  const float* Wq    = (const float*)d_in[1];
  const float* bq    = (const float*)d_in[2];
  const float* Wk    = (const float*)d_in[3];
  const float* bk    = (const float*)d_in[4];
  const float* Wv    = (const float*)d_in[5];
  const float* bv    = (const float*)d_in[6];
  const float* gamma = (const float*)d_in[7];
  float* out = (float*)d_out;

  char* wsb = (char*)d_ws;
  const size_t szQ = (size_t)BN * NN * DQK * 2;        // 512 KiB
  const size_t szV = (size_t)BN * CC * NN * 2;         // 4 MiB
  const size_t base = 2 * szQ + szV;
  auto need = [&](size_t js) {
    return base + js * ((size_t)2 * BN * NN * 4 + (size_t)BN * CC * NN * 2);
  };
  int JS = 8;
  if (ws_size < need(8)) JS = 4;
  if (ws_size < need(4)) JS = 2;
  if (ws_size < need(2)) JS = 1;

  u16* Qt = (u16*)(wsb);
  u16* Kt = (u16*)(wsb + szQ);
  u16* Vb = (u16*)(wsb + 2 * szQ);
  float* mstat = (float*)(wsb + base);
  float* lstat = (float*)(wsb + base + (size_t)JS * BN * NN * 4);
  u16* Opart = (u16*)(wsb + base + (size_t)2 * JS * BN * NN * 4);

  proj_kernel<<<dim3(BN * 128), dim3(320), 0, stream>>>(
      x, Wq, bq, Wk, bk, Wv, bv, Qt, Kt, Vb);
  flash_kernel<<<dim3(BN * 16 * JS), dim3(512), 0, stream>>>(
      Qt, Kt, Vb, Opart, mstat, lstat, JS);
  if (JS == 8)
    merge_kernel<8><<<dim3(BN * 256), dim3(256), 0, stream>>>(
        Opart, mstat, lstat, x, gamma, out);
  else if (JS == 4)
    merge_kernel<4><<<dim3(BN * 256), dim3(256), 0, stream>>>(
        Opart, mstat, lstat, x, gamma, out);
  else if (JS == 2)
    merge_kernel<2><<<dim3(BN * 256), dim3(256), 0, stream>>>(
        Opart, mstat, lstat, x, gamma, out);
  else
    merge_kernel<1><<<dim3(BN * 256), dim3(256), 0, stream>>>(
        Opart, mstat, lstat, x, gamma, out);
}

// Round 8
// 126.055 us; speedup vs baseline: 1.7297x; 1.0322x over previous
//
#include <hip/hip_runtime.h>
#include <hip/hip_bf16.h>

// ---------------------------------------------------------------------------
// SAGAN-style spatial self-attention, B=4 C=128 H=W=64 (N=4096), CQK=16.
// proj (MFMA, LDS-bounced coalesced stores) -> flash (8-wave blocks,
// LDS-shared V tiles, swapped QK^T, per-lane online softmax via permlane
// swaps + cvt_pk, JS KV-split) -> merge (u32 channel-pair partials).
// ---------------------------------------------------------------------------

#define BN 4
#define CC 128
#define NN 4096
#define DQK 16
#define KVB 64

typedef float f32x16 __attribute__((ext_vector_type(16)));
typedef short s16x8 __attribute__((ext_vector_type(8)));
typedef unsigned short u16;

union FragU { unsigned u[4]; s16x8 v; };

#if defined(__has_builtin)
#  if __has_builtin(__builtin_amdgcn_permlane32_swap)
#    define PLSWAP 1
#  endif
#endif

__device__ inline u16 to_bf16(float f) {
  unsigned u = __builtin_bit_cast(unsigned, f);
  unsigned r = u + 0x7fffu + ((u >> 16) & 1u);
  return (u16)(r >> 16);
}
// v_cvt_pk_bf16_f32: dst = {lo16=cvt(lo), hi16=cvt(hi)} (gfx950, no builtin)
__device__ inline unsigned cvt_pk(float lo, float hi) {
  unsigned r;
  asm("v_cvt_pk_bf16_f32 %0, %1, %2" : "=v"(r) : "v"(lo), "v"(hi));
  return r;
}
__device__ inline float bf16lo_f(unsigned u) {
  return __builtin_bit_cast(float, u << 16);
}
__device__ inline float bf16hi_f(unsigned u) {
  return __builtin_bit_cast(float, u & 0xffff0000u);
}

// half-swap between lane halves: new a = l<32 ? a : b[l-32];
//                                new b = l<32 ? a[l+32] : b
__device__ inline void half_swap(unsigned& a, unsigned& b) {
#ifdef PLSWAP
  auto r = __builtin_amdgcn_permlane32_swap(a, b, false, false);
  a = r[0]; b = r[1];
#else
  unsigned xa = (unsigned)__shfl_xor((int)a, 32);
  unsigned xb = (unsigned)__shfl_xor((int)b, 32);
  bool hi = (threadIdx.x & 32) != 0;
  unsigned na = hi ? xb : a;
  unsigned nb = hi ? b : xa;
  a = na; b = nb;
#endif
}
__device__ inline float max_partner(float t) {
#ifdef PLSWAP
  unsigned u = __builtin_bit_cast(unsigned, t);
  auto r = __builtin_amdgcn_permlane32_swap(u, u, false, false);
  return fmaxf(__builtin_bit_cast(float, r[0]), __builtin_bit_cast(float, r[1]));
#else
  return fmaxf(t, __shfl_xor(t, 32));
#endif
}
__device__ inline float add_partner(float t) {
#ifdef PLSWAP
  unsigned u = __builtin_bit_cast(unsigned, t);
  auto r = __builtin_amdgcn_permlane32_swap(u, u, false, false);
  return __builtin_bit_cast(float, r[0]) + __builtin_bit_cast(float, r[1]);
#else
  return t + __shfl_xor(t, 32);
#endif
}

// ---------------------------------------------------------------------------
// Kernel 1: fused QKV projection. grid = B*64 blocks x 640 threads (10 waves).
// Block owns 64 n-positions. wave = (A-tile, n-half): at0 = Q+K stacked,
// at1..4 = V row-tiles. Outputs bounced through LDS, stored coalesced.
// Writes Qt[b][n][16] (bf16, *log2e), Kt[b][n][16], Vb[b][c][n].
// ---------------------------------------------------------------------------
__global__ __launch_bounds__(640) void proj_kernel(
    const float* __restrict__ x,
    const float* __restrict__ Wq, const float* __restrict__ bq,
    const float* __restrict__ Wk, const float* __restrict__ bk,
    const float* __restrict__ Wv, const float* __restrict__ bv,
    u16* __restrict__ Qt, u16* __restrict__ Kt, u16* __restrict__ Vb)
{
  __shared__ float xs[CC][64];        // 32 KiB
  __shared__ u16 vout[CC][64];        // 16 KiB
  __shared__ u16 qkout[2][32][32];    // 4 KiB: [n-half][row: q0-15,k16-31][n32]
  const int tid = threadIdx.x;
  const int wave = tid >> 6;
  const int lane = tid & 63;
  const int l31 = lane & 31, h = lane >> 5;
  const int b = blockIdx.x >> 6;
  const int n0 = (blockIdx.x & 63) << 6;

  const float* xb = x + ((size_t)b * CC) * NN + n0;
  #pragma unroll
  for (int k = 0; k < 4; ++k) {
    int id = tid + 640 * k;
    if (id < 2048) {
      int c = id >> 4, f = (id & 15) * 4;
      *reinterpret_cast<float4*>(&xs[c][f]) =
          *reinterpret_cast<const float4*>(xb + (size_t)c * NN + f);
    }
  }
  __syncthreads();

  const int nh = wave & 1, at = wave >> 1;   // at 0..4
  const int nc = nh * 32 + l31;

  s16x8 bx[8];
  #pragma unroll
  for (int ks = 0; ks < 8; ++ks) {
    FragU f;
    #pragma unroll
    for (int q = 0; q < 4; ++q) {
      int c = 16 * ks + 8 * h + 2 * q;
      f.u[q] = cvt_pk(xs[c][nc], xs[c + 1][nc]);
    }
    bx[ks] = f.v;
  }

  f32x16 acc;
  #pragma unroll
  for (int r = 0; r < 16; ++r) acc[r] = 0.f;

  const float LOG2E = 1.44269504088896340736f;

  const float* wrow;
  if (at == 0)
    wrow = (l31 < 16) ? (Wq + (size_t)l31 * CC) : (Wk + (size_t)(l31 - 16) * CC);
  else
    wrow = Wv + (size_t)((at - 1) * 32 + l31) * CC;

  #pragma unroll
  for (int ks = 0; ks < 8; ++ks) {
    const float* wp = wrow + 16 * ks + 8 * h;
    float4 w0 = *reinterpret_cast<const float4*>(wp);
    float4 w1 = *reinterpret_cast<const float4*>(wp + 4);
    FragU a;
    a.u[0] = cvt_pk(w0.x, w0.y); a.u[1] = cvt_pk(w0.z, w0.w);
    a.u[2] = cvt_pk(w1.x, w1.y); a.u[3] = cvt_pk(w1.z, w1.w);
    acc = __builtin_amdgcn_mfma_f32_32x32x16_bf16(a.v, bx[ks], acc, 0, 0, 0);
  }

  if (at == 0) {
    #pragma unroll
    for (int r = 0; r < 16; ++r) {
      int row = (r & 3) + 8 * (r >> 2) + 4 * h;   // 0..31
      float val = acc[r];
      val = (row < 16) ? (val + bq[row]) * LOG2E : (val + bk[row - 16]);
      qkout[nh][row][l31] = to_bf16(val);
    }
  } else {
    #pragma unroll
    for (int r = 0; r < 16; ++r) {
      int e = (at - 1) * 32 + (r & 3) + 8 * (r >> 2) + 4 * h;
      vout[e][nh * 32 + l31] = to_bf16(acc[r] + bv[e]);
    }
  }
  __syncthreads();

  // Qt/Kt: 1024 u32 chunks (2 x 512), contiguous 2-KiB runs
  for (int id = tid; id < 1024; id += 640) {
    int isK = id >> 9, j = id & 511;
    int ni = j >> 3, ch = j & 7;
    int nhh = ni >> 5, n32 = ni & 31;
    unsigned lo = qkout[nhh][isK * 16 + 2 * ch][n32];
    unsigned hi = qkout[nhh][isK * 16 + 2 * ch + 1][n32];
    u16* dst = (isK ? Kt : Qt) + ((size_t)b * NN + n0 + ni) * DQK + 2 * ch;
    *reinterpret_cast<unsigned*>(dst) = lo | (hi << 16);
  }
  // Vb: 1024 16-B chunks, full 128-B lines per c-row
  for (int id = tid; id < 1024; id += 640) {
    int c = id >> 3, q16 = id & 7;
    s16x8 v = *reinterpret_cast<const s16x8*>(&vout[c][q16 * 8]);
    *reinterpret_cast<s16x8*>(Vb + ((size_t)b * CC + c) * NN + n0 + q16 * 8) = v;
  }
}

// ---------------------------------------------------------------------------
// Kernel 2: flash attention. 8-wave (512-thr) blocks; block owns 256 q-rows
// and one KV segment. V tile [128c x 64j] staged to LDS (double-buffered,
// XOR-swizzled) shared by 8 waves. Swapped QK^T keeps softmax per-lane;
// permlane32_swap for all cross-half traffic (no LDS bpermute); cvt_pk for
// P->bf16. Partials: u32 channel-pairs (full-line writes) + f32 m/l.
// ---------------------------------------------------------------------------
__global__ __launch_bounds__(512, 4) void flash_kernel(
    const u16* __restrict__ Qt, const u16* __restrict__ Kt,
    const u16* __restrict__ Vb,
    unsigned* __restrict__ Opart, float* __restrict__ mstat,
    float* __restrict__ lstat, int JS)
{
  __shared__ u16 Vs[2][CC * KVB];        // 2 x 16 KiB, swizzled 128-B rows
  const int tid = threadIdx.x;
  const int wv = tid >> 6;
  const int lane = tid & 63;
  const int l31 = lane & 31, h = lane >> 5;
  const int qb = blockIdx.x & 15;
  const int bs = blockIdx.x >> 4;
  const int b = bs / JS, sg = bs % JS;
  const int i0 = qb * 256 + wv * 32;
  const int seglen = NN / JS;
  const int j_begin = sg * seglen;
  const int niter = seglen / KVB;

  const int sc0 = tid >> 3;              // 0..63
  const int so = (tid & 7) * 16;
  const int sw0 = (sc0 & 7) << 4;

  const u16* Kb = Kt + (size_t)b * NN * DQK;
  const u16* Vbb = Vb + (size_t)b * CC * NN;

  s16x8 qf = *reinterpret_cast<const s16x8*>(
      Qt + ((size_t)b * NN + i0 + l31) * DQK + 8 * h);

  f32x16 zero;
  #pragma unroll
  for (int r = 0; r < 16; ++r) zero[r] = 0.f;
  f32x16 acc[4];
  #pragma unroll
  for (int ct = 0; ct < 4; ++ct) acc[ct] = zero;
  float m_run = -__builtin_inff();
  float l_run = 0.f;

  {
    s16x8 g0 = *reinterpret_cast<const s16x8*>(
        Vbb + (size_t)sc0 * NN + j_begin + so / 2);
    s16x8 g1 = *reinterpret_cast<const s16x8*>(
        Vbb + (size_t)(64 + sc0) * NN + j_begin + so / 2);
    *reinterpret_cast<s16x8*>(&Vs[0][sc0 * KVB + ((so ^ sw0) >> 1)]) = g0;
    *reinterpret_cast<s16x8*>(&Vs[0][(64 + sc0) * KVB + ((so ^ sw0) >> 1)]) = g1;
  }
  s16x8 kf0 = *reinterpret_cast<const s16x8*>(
      Kb + (size_t)(j_begin + l31) * DQK + 8 * h);
  s16x8 kf1 = *reinterpret_cast<const s16x8*>(
      Kb + (size_t)(j_begin + 32 + l31) * DQK + 8 * h);
  __syncthreads();

  const int rsw = (l31 & 7) << 4;

  for (int t = 0; t < niter; ++t) {
    const int cur = t & 1;
    s16x8 g0, g1, nk0, nk1;
    const bool more = (t + 1 < niter);
    if (more) {
      const int jn = j_begin + (t + 1) * KVB;
      g0 = *reinterpret_cast<const s16x8*>(
          Vbb + (size_t)sc0 * NN + jn + so / 2);
      g1 = *reinterpret_cast<const s16x8*>(
          Vbb + (size_t)(64 + sc0) * NN + jn + so / 2);
      nk0 = *reinterpret_cast<const s16x8*>(
          Kb + (size_t)(jn + l31) * DQK + 8 * h);
      nk1 = *reinterpret_cast<const s16x8*>(
          Kb + (size_t)(jn + 32 + l31) * DQK + 8 * h);
    }

    #pragma unroll
    for (int s = 0; s < 2; ++s) {
      f32x16 sv = __builtin_amdgcn_mfma_f32_32x32x16_bf16(
          s ? kf1 : kf0, qf, zero, 0, 0, 0);

      // max over 16 regs as max3-foldable triples (8 insts), then half-swap
      float t0 = fmaxf(fmaxf(sv[0], sv[1]), sv[2]);
      float t1 = fmaxf(fmaxf(sv[3], sv[4]), sv[5]);
      float t2 = fmaxf(fmaxf(sv[6], sv[7]), sv[8]);
      float t3 = fmaxf(fmaxf(sv[9], sv[10]), sv[11]);
      float t4 = fmaxf(fmaxf(sv[12], sv[13]), sv[14]);
      float u0 = fmaxf(fmaxf(t0, t1), t2);
      float u1 = fmaxf(fmaxf(t3, t4), sv[15]);
      float cmb = max_partner(fmaxf(u0, u1));
      float m_new = (cmb > m_run + 8.f) ? cmb : m_run;   // defer-max (T13)
      if (__any(m_new > m_run)) {
        float alpha = __builtin_amdgcn_exp2f(m_run - m_new);
        l_run *= alpha;
        #pragma unroll
        for (int ct = 0; ct < 4; ++ct)
          #pragma unroll
          for (int r = 0; r < 16; ++r) acc[ct][r] *= alpha;
        m_run = m_new;
      }

      float p[16];
      #pragma unroll
      for (int r = 0; r < 16; ++r)
        p[r] = __builtin_amdgcn_exp2f(sv[r] - m_run);
      float s01 = p[0] + p[1],  s23 = p[2] + p[3];
      float s45 = p[4] + p[5],  s67 = p[6] + p[7];
      float s89 = p[8] + p[9],  sab = p[10] + p[11];
      float scd = p[12] + p[13], sef = p[14] + p[15];
      l_run += ((s01 + s23) + (s45 + s67)) + ((s89 + sab) + (scd + sef));

      // pack to bf16 pairs (cvt_pk), build frags via permlane half-swaps
      unsigned w0_ = cvt_pk(p[0], p[1]),  w1_ = cvt_pk(p[2], p[3]);
      unsigned w2_ = cvt_pk(p[4], p[5]),  w3_ = cvt_pk(p[6], p[7]);
      unsigned w4_ = cvt_pk(p[8], p[9]),  w5_ = cvt_pk(p[10], p[11]);
      unsigned w6_ = cvt_pk(p[12], p[13]), w7_ = cvt_pk(p[14], p[15]);
      half_swap(w0_, w2_);   // -> f0.u[0], f0.u[2]
      half_swap(w1_, w3_);   // -> f0.u[1], f0.u[3]
      half_swap(w4_, w6_);   // -> f1.u[0], f1.u[2]
      half_swap(w5_, w7_);   // -> f1.u[1], f1.u[3]
      FragU f0, f1;
      f0.u[0] = w0_; f0.u[1] = w1_; f0.u[2] = w2_; f0.u[3] = w3_;
      f1.u[0] = w4_; f1.u[1] = w5_; f1.u[2] = w6_; f1.u[3] = w7_;

      #pragma unroll
      for (int ct = 0; ct < 4; ++ct) {
        const int c = 32 * ct + l31;
        s16x8 va = *reinterpret_cast<const s16x8*>(
            &Vs[cur][c * KVB + (((s * 64 + h * 16) ^ rsw) >> 1)]);
        s16x8 vb2 = *reinterpret_cast<const s16x8*>(
            &Vs[cur][c * KVB + (((s * 64 + 32 + h * 16) ^ rsw) >> 1)]);
        acc[ct] = __builtin_amdgcn_mfma_f32_32x32x16_bf16(va, f0.v,
                                                          acc[ct], 0, 0, 0);
        acc[ct] = __builtin_amdgcn_mfma_f32_32x32x16_bf16(vb2, f1.v,
                                                          acc[ct], 0, 0, 0);
      }
    }

    if (more) {
      *reinterpret_cast<s16x8*>(
          &Vs[cur ^ 1][sc0 * KVB + ((so ^ sw0) >> 1)]) = g0;
      *reinterpret_cast<s16x8*>(
          &Vs[cur ^ 1][(64 + sc0) * KVB + ((so ^ sw0) >> 1)]) = g1;
      kf0 = nk0; kf1 = nk1;
    }
    __syncthreads();
  }

  float l_tot = add_partner(l_run);

  // u32 channel-pair partials: full 128-B line per (ct,q) store
  unsigned* Ob = Opart + ((size_t)(b * JS + sg) * 64) * NN;
  #pragma unroll
  for (int ct = 0; ct < 4; ++ct)
    #pragma unroll
    for (int q = 0; q < 8; ++q) {
      unsigned pv = cvt_pk(acc[ct][2 * q], acc[ct][2 * q + 1]);
      int c = 32 * ct + ((2 * q) & 3) + 8 * (q >> 1) + 4 * h;   // even
      Ob[(size_t)(c >> 1) * NN + i0 + l31] = pv;
    }
  if (lane < 32) {
    mstat[((size_t)(b * JS + sg)) * NN + i0 + l31] = m_run;
    lstat[((size_t)(b * JS + sg)) * NN + i0 + l31] = l_tot;
  }
}

// ---------------------------------------------------------------------------
// Kernel 3: merge u32 channel-pair partials, normalize, out = gamma*O + x.
// grid = B*256 blocks x 256 threads; thread = 2 i x 4 channels (2 c-pairs).
// ---------------------------------------------------------------------------
template <int JS>
__global__ __launch_bounds__(256) void merge_kernel(
    const unsigned* __restrict__ Opart, const float* __restrict__ mstat,
    const float* __restrict__ lstat, const float* __restrict__ x,
    const float* __restrict__ gamma, float* __restrict__ out)
{
  const int tid = threadIdx.x;
  const int il = tid & 63;
  const int cg = tid >> 6;                   // 0..3
  const int bid = blockIdx.x;
  const int b = bid >> 8;
  const int rem = bid & 255;
  const int i = (((rem >> 3) << 6) + il) * 2;     // even i, pair (i, i+1)
  const int c2 = ((rem & 7) * 4 + cg) * 2;        // c-pairs c2, c2+1

  float m0 = -__builtin_inff(), m1 = m0;
  float ms0[JS], ms1[JS];
  #pragma unroll
  for (int s = 0; s < JS; ++s) {
    const float* mp = mstat + ((size_t)(b * JS + s)) * NN + i;
    ms0[s] = mp[0]; ms1[s] = mp[1];
    m0 = fmaxf(m0, ms0[s]); m1 = fmaxf(m1, ms1[s]);
  }
  float d0 = 0.f, d1 = 0.f;
  float w0[JS], w1[JS];
  #pragma unroll
  for (int s = 0; s < JS; ++s) {
    const float* lp = lstat + ((size_t)(b * JS + s)) * NN + i;
    w0[s] = __builtin_amdgcn_exp2f(ms0[s] - m0);
    w1[s] = __builtin_amdgcn_exp2f(ms1[s] - m1);
    d0 += w0[s] * lp[0];
    d1 += w1[s] * lp[1];
  }
  const float g = gamma[0];
  const float g0 = g / d0, g1 = g / d1;
  #pragma unroll
  for (int s = 0; s < JS; ++s) { w0[s] *= g0; w1[s] *= g1; }

  float o[4][2] = {{0.f, 0.f}, {0.f, 0.f}, {0.f, 0.f}, {0.f, 0.f}};
  #pragma unroll
  for (int s = 0; s < JS; ++s) {
    const unsigned* Ob = Opart + ((size_t)(b * JS + s) * 64) * NN;
    uint2 A = *reinterpret_cast<const uint2*>(&Ob[(size_t)c2 * NN + i]);
    uint2 Bv = *reinterpret_cast<const uint2*>(&Ob[(size_t)(c2 + 1) * NN + i]);
    o[0][0] += w0[s] * bf16lo_f(A.x);  o[1][0] += w0[s] * bf16hi_f(A.x);
    o[0][1] += w1[s] * bf16lo_f(A.y);  o[1][1] += w1[s] * bf16hi_f(A.y);
    o[2][0] += w0[s] * bf16lo_f(Bv.x); o[3][0] += w0[s] * bf16hi_f(Bv.x);
    o[2][1] += w1[s] * bf16lo_f(Bv.y); o[3][1] += w1[s] * bf16hi_f(Bv.y);
  }
  #pragma unroll
  for (int cc = 0; cc < 4; ++cc) {
    size_t oidx = ((size_t)b * CC + 2 * c2 + cc) * NN + i;
    float2 xv = *reinterpret_cast<const float2*>(x + oidx);
    float2 ov; ov.x = o[cc][0] + xv.x; ov.y = o[cc][1] + xv.y;
    *reinterpret_cast<float2*>(out + oidx) = ov;
  }
}

// ---------------------------------------------------------------------------
extern "C" void kernel_launch(void* const* d_in, const int* in_sizes, int n_in,
                              void* d_out, int out_size, void* d_ws,
                              size_t ws_size, hipStream_t stream)
{
  const float* x     = (const float*)d_in[0];
  const float* Wq    = (const float*)d_in[1];
  const float* bq    = (const float*)d_in[2];
  const float* Wk    = (const float*)d_in[3];
  const float* bk    = (const float*)d_in[4];
  const float* Wv    = (const float*)d_in[5];
  const float* bv    = (const float*)d_in[6];
  const float* gamma = (const float*)d_in[7];
  float* out = (float*)d_out;

  char* wsb = (char*)d_ws;
  const size_t szQ = (size_t)BN * NN * DQK * 2;        // 512 KiB
  const size_t szV = (size_t)BN * CC * NN * 2;         // 4 MiB
  const size_t base = 2 * szQ + szV;
  auto need = [&](size_t js) {
    return base + js * ((size_t)2 * BN * NN * 4 + (size_t)BN * 64 * NN * 4);
  };
  int JS = 8;
  if (ws_size < need(8)) JS = 4;
  if (ws_size < need(4)) JS = 2;
  if (ws_size < need(2)) JS = 1;

  u16* Qt = (u16*)(wsb);
  u16* Kt = (u16*)(wsb + szQ);
  u16* Vb = (u16*)(wsb + 2 * szQ);
  float* mstat = (float*)(wsb + base);
  float* lstat = (float*)(wsb + base + (size_t)JS * BN * NN * 4);
  unsigned* Opart = (unsigned*)(wsb + base + (size_t)2 * JS * BN * NN * 4);

  proj_kernel<<<dim3(BN * 64), dim3(640), 0, stream>>>(
      x, Wq, bq, Wk, bk, Wv, bv, Qt, Kt, Vb);
  flash_kernel<<<dim3(BN * 16 * JS), dim3(512), 0, stream>>>(
      Qt, Kt, Vb, Opart, mstat, lstat, JS);
  if (JS == 8)
    merge_kernel<8><<<dim3(BN * 256), dim3(256), 0, stream>>>(
        Opart, mstat, lstat, x, gamma, out);
  else if (JS == 4)
    merge_kernel<4><<<dim3(BN * 256), dim3(256), 0, stream>>>(
        Opart, mstat, lstat, x, gamma, out);
  else if (JS == 2)
    merge_kernel<2><<<dim3(BN * 256), dim3(256), 0, stream>>>(
        Opart, mstat, lstat, x, gamma, out);
  else
    merge_kernel<1><<<dim3(BN * 256), dim3(256), 0, stream>>>(
        Opart, mstat, lstat, x, gamma, out);
}

// Round 10
// 116.722 us; speedup vs baseline: 1.8680x; 1.0800x over previous
//
#include <hip/hip_runtime.h>
#include <hip/hip_bf16.h>

// ---------------------------------------------------------------------------
// SAGAN-style spatial self-attention, B=4 C=128 H=W=64 (N=4096), CQK=16.
// proj (MFMA, LDS-bounced coalesced stores) -> flash (8-wave blocks,
// LDS-shared V+K tiles, swapped QK^T, per-lane online softmax via permlane
// swaps + cvt_pk, JS KV-split) -> merge (u32 channel-pair partials).
// ---------------------------------------------------------------------------

#define BN 4
#define CC 128
#define NN 4096
#define DQK 16
#define KVB 64

typedef float f32x16 __attribute__((ext_vector_type(16)));
typedef short s16x8 __attribute__((ext_vector_type(8)));
typedef unsigned short u16;

union FragU { unsigned u[4]; s16x8 v; };

#if defined(__has_builtin)
#  if __has_builtin(__builtin_amdgcn_permlane32_swap)
#    define PLSWAP 1
#  endif
#endif

__device__ inline u16 to_bf16(float f) {
  unsigned u = __builtin_bit_cast(unsigned, f);
  unsigned r = u + 0x7fffu + ((u >> 16) & 1u);
  return (u16)(r >> 16);
}
// v_cvt_pk_bf16_f32: dst = {lo16=cvt(lo), hi16=cvt(hi)} (gfx950, no builtin)
__device__ inline unsigned cvt_pk(float lo, float hi) {
  unsigned r;
  asm("v_cvt_pk_bf16_f32 %0, %1, %2" : "=v"(r) : "v"(lo), "v"(hi));
  return r;
}
__device__ inline float bf16lo_f(unsigned u) {
  return __builtin_bit_cast(float, u << 16);
}
__device__ inline float bf16hi_f(unsigned u) {
  return __builtin_bit_cast(float, u & 0xffff0000u);
}

// half-swap between lane halves: new a = l<32 ? a : b[l-32];
//                                new b = l<32 ? a[l+32] : b
__device__ inline void half_swap(unsigned& a, unsigned& b) {
#ifdef PLSWAP
  auto r = __builtin_amdgcn_permlane32_swap(a, b, false, false);
  a = r[0]; b = r[1];
#else
  unsigned xa = (unsigned)__shfl_xor((int)a, 32);
  unsigned xb = (unsigned)__shfl_xor((int)b, 32);
  bool hi = (threadIdx.x & 32) != 0;
  unsigned na = hi ? xb : a;
  unsigned nb = hi ? b : xa;
  a = na; b = nb;
#endif
}
__device__ inline float max_partner(float t) {
#ifdef PLSWAP
  unsigned u = __builtin_bit_cast(unsigned, t);
  auto r = __builtin_amdgcn_permlane32_swap(u, u, false, false);
  return fmaxf(__builtin_bit_cast(float, r[0]), __builtin_bit_cast(float, r[1]));
#else
  return fmaxf(t, __shfl_xor(t, 32));
#endif
}
__device__ inline float add_partner(float t) {
#ifdef PLSWAP
  unsigned u = __builtin_bit_cast(unsigned, t);
  auto r = __builtin_amdgcn_permlane32_swap(u, u, false, false);
  return __builtin_bit_cast(float, r[0]) + __builtin_bit_cast(float, r[1]);
#else
  return t + __shfl_xor(t, 32);
#endif
}

// ---------------------------------------------------------------------------
// Kernel 1: fused QKV projection. grid = B*64 blocks x 640 threads (10 waves).
// Block owns 64 n-positions. wave = (A-tile, n-half): at0 = Q+K stacked,
// at1..4 = V row-tiles. Outputs bounced through LDS, stored coalesced.
// Writes Qt[b][n][16] (bf16, *log2e), Kt[b][n][16], Vb[b][c][n].
// ---------------------------------------------------------------------------
__global__ __launch_bounds__(640) void proj_kernel(
    const float* __restrict__ x,
    const float* __restrict__ Wq, const float* __restrict__ bq,
    const float* __restrict__ Wk, const float* __restrict__ bk,
    const float* __restrict__ Wv, const float* __restrict__ bv,
    u16* __restrict__ Qt, u16* __restrict__ Kt, u16* __restrict__ Vb)
{
  __shared__ float xs[CC][64];        // 32 KiB
  __shared__ u16 vout[CC][64];        // 16 KiB
  __shared__ u16 qkout[2][32][32];    // 4 KiB: [n-half][row: q0-15,k16-31][n32]
  const int tid = threadIdx.x;
  const int wave = tid >> 6;
  const int lane = tid & 63;
  const int l31 = lane & 31, h = lane >> 5;
  const int b = blockIdx.x >> 6;
  const int n0 = (blockIdx.x & 63) << 6;

  const float* xb = x + ((size_t)b * CC) * NN + n0;
  #pragma unroll
  for (int k = 0; k < 4; ++k) {
    int id = tid + 640 * k;
    if (id < 2048) {
      int c = id >> 4, f = (id & 15) * 4;
      *reinterpret_cast<float4*>(&xs[c][f]) =
          *reinterpret_cast<const float4*>(xb + (size_t)c * NN + f);
    }
  }
  __syncthreads();

  const int nh = wave & 1, at = wave >> 1;   // at 0..4
  const int nc = nh * 32 + l31;

  s16x8 bx[8];
  #pragma unroll
  for (int ks = 0; ks < 8; ++ks) {
    FragU f;
    #pragma unroll
    for (int q = 0; q < 4; ++q) {
      int c = 16 * ks + 8 * h + 2 * q;
      f.u[q] = cvt_pk(xs[c][nc], xs[c + 1][nc]);
    }
    bx[ks] = f.v;
  }

  f32x16 acc;
  #pragma unroll
  for (int r = 0; r < 16; ++r) acc[r] = 0.f;

  const float LOG2E = 1.44269504088896340736f;

  const float* wrow;
  if (at == 0)
    wrow = (l31 < 16) ? (Wq + (size_t)l31 * CC) : (Wk + (size_t)(l31 - 16) * CC);
  else
    wrow = Wv + (size_t)((at - 1) * 32 + l31) * CC;

  #pragma unroll
  for (int ks = 0; ks < 8; ++ks) {
    const float* wp = wrow + 16 * ks + 8 * h;
    float4 w0 = *reinterpret_cast<const float4*>(wp);
    float4 w1 = *reinterpret_cast<const float4*>(wp + 4);
    FragU a;
    a.u[0] = cvt_pk(w0.x, w0.y); a.u[1] = cvt_pk(w0.z, w0.w);
    a.u[2] = cvt_pk(w1.x, w1.y); a.u[3] = cvt_pk(w1.z, w1.w);
    acc = __builtin_amdgcn_mfma_f32_32x32x16_bf16(a.v, bx[ks], acc, 0, 0, 0);
  }

  if (at == 0) {
    #pragma unroll
    for (int r = 0; r < 16; ++r) {
      int row = (r & 3) + 8 * (r >> 2) + 4 * h;   // 0..31
      float val = acc[r];
      val = (row < 16) ? (val + bq[row]) * LOG2E : (val + bk[row - 16]);
      qkout[nh][row][l31] = to_bf16(val);
    }
  } else {
    #pragma unroll
    for (int r = 0; r < 16; ++r) {
      int e = (at - 1) * 32 + (r & 3) + 8 * (r >> 2) + 4 * h;
      vout[e][nh * 32 + l31] = to_bf16(acc[r] + bv[e]);
    }
  }
  __syncthreads();

  // Qt/Kt: 1024 u32 chunks (2 x 512), contiguous 2-KiB runs
  for (int id = tid; id < 1024; id += 640) {
    int isK = id >> 9, j = id & 511;
    int ni = j >> 3, ch = j & 7;
    int nhh = ni >> 5, n32 = ni & 31;
    unsigned lo = qkout[nhh][isK * 16 + 2 * ch][n32];
    unsigned hi = qkout[nhh][isK * 16 + 2 * ch + 1][n32];
    u16* dst = (isK ? Kt : Qt) + ((size_t)b * NN + n0 + ni) * DQK + 2 * ch;
    *reinterpret_cast<unsigned*>(dst) = lo | (hi << 16);
  }
  // Vb: 1024 16-B chunks, full 128-B lines per c-row
  for (int id = tid; id < 1024; id += 640) {
    int c = id >> 3, q16 = id & 7;
    s16x8 v = *reinterpret_cast<const s16x8*>(&vout[c][q16 * 8]);
    *reinterpret_cast<s16x8*>(Vb + ((size_t)b * CC + c) * NN + n0 + q16 * 8) = v;
  }
}

// ---------------------------------------------------------------------------
// Kernel 2: flash attention. 8-wave (512-thr) blocks; block owns 256 q-rows
// and one KV segment. V tile [128c x 64j] AND K tile [64j x 16d] staged to
// LDS (double-buffered, swizzled) shared by 8 waves — NO scattered global
// loads in the main loop (K tile is a contiguous 2-KiB run). Global loads
// issued at loop top, LDS writes after compute (T14), one barrier per iter.
// Swapped QK^T keeps softmax per-lane; permlane32_swap for cross-half
// traffic; cvt_pk for P->bf16. Partials: u32 channel-pairs + f32 m/l.
// ---------------------------------------------------------------------------
__global__ __launch_bounds__(512, 4) void flash_kernel(
    const u16* __restrict__ Qt, const u16* __restrict__ Kt,
    const u16* __restrict__ Vb,
    unsigned* __restrict__ Opart, float* __restrict__ mstat,
    float* __restrict__ lstat, int JS)
{
  __shared__ u16 Vs[2][CC * KVB];        // 2 x 16 KiB, swizzled 128-B rows
  __shared__ u16 Ks[2][KVB * DQK];       // 2 x 2 KiB, 1-bit half-swizzle
  const int tid = threadIdx.x;
  const int wv = tid >> 6;
  const int lane = tid & 63;
  const int l31 = lane & 31, h = lane >> 5;
  const int qb = blockIdx.x & 15;
  const int bs = blockIdx.x >> 4;
  const int b = bs / JS, sg = bs % JS;
  const int i0 = qb * 256 + wv * 32;
  const int seglen = NN / JS;
  const int j_begin = sg * seglen;
  const int niter = seglen / KVB;

  const int sc0 = tid >> 3;              // 0..63
  const int so = (tid & 7) * 16;
  const int sw0 = (sc0 & 7) << 4;

  const u16* Kb = Kt + (size_t)b * NN * DQK;
  const u16* Vbb = Vb + (size_t)b * CC * NN;

  // K stage coords (threads 0..127): row = p>>1, half = p&1, swizzled slot
  const int kp_row = tid >> 1, kp_half = tid & 1;
  const int kp_slot = kp_row * DQK + ((kp_half ^ (kp_row & 1)) << 3);

  s16x8 qf = *reinterpret_cast<const s16x8*>(
      Qt + ((size_t)b * NN + i0 + l31) * DQK + 8 * h);

  f32x16 zero;
  #pragma unroll
  for (int r = 0; r < 16; ++r) zero[r] = 0.f;
  f32x16 acc[4];
  #pragma unroll
  for (int ct = 0; ct < 4; ++ct) acc[ct] = zero;
  float m_run = -__builtin_inff();
  float l_run = 0.f;

  // prologue: stage V0 and K0
  {
    s16x8 g0 = *reinterpret_cast<const s16x8*>(
        Vbb + (size_t)sc0 * NN + j_begin + so / 2);
    s16x8 g1 = *reinterpret_cast<const s16x8*>(
        Vbb + (size_t)(64 + sc0) * NN + j_begin + so / 2);
    *reinterpret_cast<s16x8*>(&Vs[0][sc0 * KVB + ((so ^ sw0) >> 1)]) = g0;
    *reinterpret_cast<s16x8*>(&Vs[0][(64 + sc0) * KVB + ((so ^ sw0) >> 1)]) = g1;
    if (tid < 128) {
      s16x8 gk = *reinterpret_cast<const s16x8*>(
          Kb + (size_t)j_begin * DQK + tid * 8);
      *reinterpret_cast<s16x8*>(&Ks[0][kp_slot]) = gk;
    }
  }
  __syncthreads();

  const int rsw = (l31 & 7) << 4;
  // K read slots (u16 idx): row = s*32 + l31
  const int kr0 = l31 * DQK + ((h ^ (l31 & 1)) << 3);
  const int kr1 = (32 + l31) * DQK + ((h ^ (l31 & 1)) << 3);

  for (int t = 0; t < niter; ++t) {
    const int cur = t & 1;
    s16x8 g0, g1, gk;
    const bool more = (t + 1 < niter);
    if (more) {
      const int jn = j_begin + (t + 1) * KVB;
      g0 = *reinterpret_cast<const s16x8*>(
          Vbb + (size_t)sc0 * NN + jn + so / 2);
      g1 = *reinterpret_cast<const s16x8*>(
          Vbb + (size_t)(64 + sc0) * NN + jn + so / 2);
      if (tid < 128)
        gk = *reinterpret_cast<const s16x8*>(
            Kb + (size_t)jn * DQK + tid * 8);
    }

    // K frags from LDS (contiguous-staged, mild 4-way conflict)
    s16x8 kf0 = *reinterpret_cast<const s16x8*>(&Ks[cur][kr0]);
    s16x8 kf1 = *reinterpret_cast<const s16x8*>(&Ks[cur][kr1]);

    #pragma unroll
    for (int s = 0; s < 2; ++s) {
      f32x16 sv = __builtin_amdgcn_mfma_f32_32x32x16_bf16(
          s ? kf1 : kf0, qf, zero, 0, 0, 0);

      // max over 16 regs as max3-foldable triples (8 insts), then half-swap
      float t0 = fmaxf(fmaxf(sv[0], sv[1]), sv[2]);
      float t1 = fmaxf(fmaxf(sv[3], sv[4]), sv[5]);
      float t2 = fmaxf(fmaxf(sv[6], sv[7]), sv[8]);
      float t3 = fmaxf(fmaxf(sv[9], sv[10]), sv[11]);
      float t4 = fmaxf(fmaxf(sv[12], sv[13]), sv[14]);
      float u0 = fmaxf(fmaxf(t0, t1), t2);
      float u1 = fmaxf(fmaxf(t3, t4), sv[15]);
      float cmb = max_partner(fmaxf(u0, u1));
      float m_new = (cmb > m_run + 8.f) ? cmb : m_run;   // defer-max (T13)
      if (__any(m_new > m_run)) {
        float alpha = __builtin_amdgcn_exp2f(m_run - m_new);
        l_run *= alpha;
        #pragma unroll
        for (int ct = 0; ct < 4; ++ct)
          #pragma unroll
          for (int r = 0; r < 16; ++r) acc[ct][r] *= alpha;
        m_run = m_new;
      }

      float p[16];
      #pragma unroll
      for (int r = 0; r < 16; ++r)
        p[r] = __builtin_amdgcn_exp2f(sv[r] - m_run);
      float s01 = p[0] + p[1],  s23 = p[2] + p[3];
      float s45 = p[4] + p[5],  s67 = p[6] + p[7];
      float s89 = p[8] + p[9],  sab = p[10] + p[11];
      float scd = p[12] + p[13], sef = p[14] + p[15];
      l_run += ((s01 + s23) + (s45 + s67)) + ((s89 + sab) + (scd + sef));

      // pack to bf16 pairs (cvt_pk), build frags via permlane half-swaps
      unsigned w0_ = cvt_pk(p[0], p[1]),  w1_ = cvt_pk(p[2], p[3]);
      unsigned w2_ = cvt_pk(p[4], p[5]),  w3_ = cvt_pk(p[6], p[7]);
      unsigned w4_ = cvt_pk(p[8], p[9]),  w5_ = cvt_pk(p[10], p[11]);
      unsigned w6_ = cvt_pk(p[12], p[13]), w7_ = cvt_pk(p[14], p[15]);
      half_swap(w0_, w2_);   // -> f0.u[0], f0.u[2]
      half_swap(w1_, w3_);   // -> f0.u[1], f0.u[3]
      half_swap(w4_, w6_);   // -> f1.u[0], f1.u[2]
      half_swap(w5_, w7_);   // -> f1.u[1], f1.u[3]
      FragU f0, f1;
      f0.u[0] = w0_; f0.u[1] = w1_; f0.u[2] = w2_; f0.u[3] = w3_;
      f1.u[0] = w4_; f1.u[1] = w5_; f1.u[2] = w6_; f1.u[3] = w7_;

      #pragma unroll
      for (int ct = 0; ct < 4; ++ct) {
        const int c = 32 * ct + l31;
        s16x8 va = *reinterpret_cast<const s16x8*>(
            &Vs[cur][c * KVB + (((s * 64 + h * 16) ^ rsw) >> 1)]);
        s16x8 vb2 = *reinterpret_cast<const s16x8*>(
            &Vs[cur][c * KVB + (((s * 64 + 32 + h * 16) ^ rsw) >> 1)]);
        acc[ct] = __builtin_amdgcn_mfma_f32_32x32x16_bf16(va, f0.v,
                                                          acc[ct], 0, 0, 0);
        acc[ct] = __builtin_amdgcn_mfma_f32_32x32x16_bf16(vb2, f1.v,
                                                          acc[ct], 0, 0, 0);
      }
    }

    if (more) {
      *reinterpret_cast<s16x8*>(
          &Vs[cur ^ 1][sc0 * KVB + ((so ^ sw0) >> 1)]) = g0;
      *reinterpret_cast<s16x8*>(
          &Vs[cur ^ 1][(64 + sc0) * KVB + ((so ^ sw0) >> 1)]) = g1;
      if (tid < 128)
        *reinterpret_cast<s16x8*>(&Ks[cur ^ 1][kp_slot]) = gk;
    }
    __syncthreads();
  }

  float l_tot = add_partner(l_run);

  // u32 channel-pair partials: full 128-B line per (ct,q) store
  unsigned* Ob = Opart + ((size_t)(b * JS + sg) * 64) * NN;
  #pragma unroll
  for (int ct = 0; ct < 4; ++ct)
    #pragma unroll
    for (int q = 0; q < 8; ++q) {
      unsigned pv = cvt_pk(acc[ct][2 * q], acc[ct][2 * q + 1]);
      int c = 32 * ct + ((2 * q) & 3) + 8 * (q >> 1) + 4 * h;   // even
      Ob[(size_t)(c >> 1) * NN + i0 + l31] = pv;
    }
  if (lane < 32) {
    mstat[((size_t)(b * JS + sg)) * NN + i0 + l31] = m_run;
    lstat[((size_t)(b * JS + sg)) * NN + i0 + l31] = l_tot;
  }
}

// ---------------------------------------------------------------------------
// Kernel 3: merge u32 channel-pair partials, normalize, out = gamma*O + x.
// grid = B*256 blocks x 256 threads; thread = 2 i x 4 channels (2 c-pairs).
// ---------------------------------------------------------------------------
template <int JS>
__global__ __launch_bounds__(256) void merge_kernel(
    const unsigned* __restrict__ Opart, const float* __restrict__ mstat,
    const float* __restrict__ lstat, const float* __restrict__ x,
    const float* __restrict__ gamma, float* __restrict__ out)
{
  const int tid = threadIdx.x;
  const int il = tid & 63;
  const int cg = tid >> 6;                   // 0..3
  const int bid = blockIdx.x;
  const int b = bid >> 8;
  const int rem = bid & 255;
  const int i = (((rem >> 3) << 6) + il) * 2;     // even i, pair (i, i+1)
  const int c2 = ((rem & 7) * 4 + cg) * 2;        // c-pairs c2, c2+1

  float m0 = -__builtin_inff(), m1 = m0;
  float ms0[JS], ms1[JS];
  #pragma unroll
  for (int s = 0; s < JS; ++s) {
    const float* mp = mstat + ((size_t)(b * JS + s)) * NN + i;
    ms0[s] = mp[0]; ms1[s] = mp[1];
    m0 = fmaxf(m0, ms0[s]); m1 = fmaxf(m1, ms1[s]);
  }
  float d0 = 0.f, d1 = 0.f;
  float w0[JS], w1[JS];
  #pragma unroll
  for (int s = 0; s < JS; ++s) {
    const float* lp = lstat + ((size_t)(b * JS + s)) * NN + i;
    w0[s] = __builtin_amdgcn_exp2f(ms0[s] - m0);
    w1[s] = __builtin_amdgcn_exp2f(ms1[s] - m1);
    d0 += w0[s] * lp[0];
    d1 += w1[s] * lp[1];
  }
  const float g = gamma[0];
  const float g0 = g / d0, g1 = g / d1;
  #pragma unroll
  for (int s = 0; s < JS; ++s) { w0[s] *= g0; w1[s] *= g1; }

  float o[4][2] = {{0.f, 0.f}, {0.f, 0.f}, {0.f, 0.f}, {0.f, 0.f}};
  #pragma unroll
  for (int s = 0; s < JS; ++s) {
    const unsigned* Ob = Opart + ((size_t)(b * JS + s) * 64) * NN;
    uint2 A = *reinterpret_cast<const uint2*>(&Ob[(size_t)c2 * NN + i]);
    uint2 Bv = *reinterpret_cast<const uint2*>(&Ob[(size_t)(c2 + 1) * NN + i]);
    o[0][0] += w0[s] * bf16lo_f(A.x);  o[1][0] += w0[s] * bf16hi_f(A.x);
    o[0][1] += w1[s] * bf16lo_f(A.y);  o[1][1] += w1[s] * bf16hi_f(A.y);
    o[2][0] += w0[s] * bf16lo_f(Bv.x); o[3][0] += w0[s] * bf16hi_f(Bv.x);
    o[2][1] += w1[s] * bf16lo_f(Bv.y); o[3][1] += w1[s] * bf16hi_f(Bv.y);
  }
  #pragma unroll
  for (int cc = 0; cc < 4; ++cc) {
    size_t oidx = ((size_t)b * CC + 2 * c2 + cc) * NN + i;
    float2 xv = *reinterpret_cast<const float2*>(x + oidx);
    float2 ov; ov.x = o[cc][0] + xv.x; ov.y = o[cc][1] + xv.y;
    *reinterpret_cast<float2*>(out + oidx) = ov;
  }
}

// ---------------------------------------------------------------------------
extern "C" void kernel_launch(void* const* d_in, const int* in_sizes, int n_in,
                              void* d_out, int out_size, void* d_ws,
                              size_t ws_size, hipStream_t stream)
{
  const float* x     = (const float*)d_in[0];
  const float* Wq    = (const float*)d_in[1];
  const float* bq    = (const float*)d_in[2];
  const float* Wk    = (const float*)d_in[3];
  const float* bk    = (const float*)d_in[4];
  const float* Wv    = (const float*)d_in[5];
  const float* bv    = (const float*)d_in[6];
  const float* gamma = (const float*)d_in[7];
  float* out = (float*)d_out;

  char* wsb = (char*)d_ws;
  const size_t szQ = (size_t)BN * NN * DQK * 2;        // 512 KiB
  const size_t szV = (size_t)BN * CC * NN * 2;         // 4 MiB
  const size_t base = 2 * szQ + szV;
  auto need = [&](size_t js) {
    return base + js * ((size_t)2 * BN * NN * 4 + (size_t)BN * 64 * NN * 4);
  };
  int JS = 8;
  if (ws_size < need(8)) JS = 4;
  if (ws_size < need(4)) JS = 2;
  if (ws_size < need(2)) JS = 1;

  u16* Qt = (u16*)(wsb);
  u16* Kt = (u16*)(wsb + szQ);
  u16* Vb = (u16*)(wsb + 2 * szQ);
  float* mstat = (float*)(wsb + base);
  float* lstat = (float*)(wsb + base + (size_t)JS * BN * NN * 4);
  unsigned* Opart = (unsigned*)(wsb + base + (size_t)2 * JS * BN * NN * 4);

  proj_kernel<<<dim3(BN * 64), dim3(640), 0, stream>>>(
      x, Wq, bq, Wk, bk, Wv, bv, Qt, Kt, Vb);
  flash_kernel<<<dim3(BN * 16 * JS), dim3(512), 0, stream>>>(
      Qt, Kt, Vb, Opart, mstat, lstat, JS);
  if (JS == 8)
    merge_kernel<8><<<dim3(BN * 256), dim3(256), 0, stream>>>(
        Opart, mstat, lstat, x, gamma, out);
  else if (JS == 4)
    merge_kernel<4><<<dim3(BN * 256), dim3(256), 0, stream>>>(
        Opart, mstat, lstat, x, gamma, out);
  else if (JS == 2)
    merge_kernel<2><<<dim3(BN * 256), dim3(256), 0, stream>>>(
        Opart, mstat, lstat, x, gamma, out);
  else
    merge_kernel<1><<<dim3(BN * 256), dim3(256), 0, stream>>>(
        Opart, mstat, lstat, x, gamma, out);
}